// Round 13
// baseline (67.494 us; speedup 1.0000x reference)
//
#include <hip/hip_runtime.h>

// Algebraic collapse (verified exactly, absmax 0.0 across rounds):
//   softmax over the QUERY axis => sum_q attn[b,q,k] == 1 for all (b,k), so
//   context.mean(axis=0) = mean_k V[k,b,:] = xbar @ Wv.T + bv, and
//   out[b,h] = xbar[b,h] + sum_j xbar[b,j]*Wv[h,j] + bv[h],  xbar = x.mean(0).
//   Wq, bq, Wk, bk drop out of the output entirely.
// Lessons:
//   R2: NO cooperative grid.sync on MI355X (~100us/sync).
//   R3-R12 colsum scan: best = 512blk/4KB-run/SCHUNK=32/part=2MiB + nt loads
//     (23.6us). Occupancy not the limiter (R12: 1024blk neutral). NOTE: the
//     "slow configs" (R3/R4/R8/R9, +12us) all ALSO changed k_reduce fold
//     depth (64-256 iters) — fold cost is a confound; contiguous colsum
//     (R9) was never fairly measured.
//   R7: k_out wave-per-(h,8b) Wv-register-reuse. FROZEN.
//   R13 INSTRUMENTATION: launch k_colsum 5x (idempotent, deterministic).
//     dT = 4*(colsum+gap) => exact per-dispatch cost; 5 colsum dispatches
//     may also surface in rocprof top-5 with direct FETCH/bw numbers.

constexpr int S = 1024;
constexpr int B = 16;
constexpr int H = 1024;
constexpr int C = B * H;            // 16384 columns when x is viewed [S][B*H]
constexpr int C4 = C / 4;           // 4096 float4 columns
constexpr int SPLITS = 32;          // S-axis split (frozen good value)
constexpr int SCHUNK = S / SPLITS;  // 32 rows per block

typedef float f4v __attribute__((ext_vector_type(4)));

// --- K1 (R11 byte-identical): partial column sums, nt loads.
// grid (16, 32) = 512 blocks, block 256.
__global__ void __launch_bounds__(256) k_colsum(const f4v* __restrict__ x4,
                                                f4v* __restrict__ part4) {
    const int c4 = blockIdx.x * 256 + threadIdx.x;   // [0, 4096)
    const int split = blockIdx.y;
    const f4v* p = x4 + (size_t)split * SCHUNK * C4 + c4;
    f4v a = (f4v){0.f, 0.f, 0.f, 0.f};
#pragma unroll
    for (int i = 0; i < SCHUNK; ++i) {
        f4v v = __builtin_nontemporal_load(p + (size_t)i * C4);
        a += v;   // same per-column add order as R11
    }
    part4[(size_t)split * C4 + c4] = a;
}

// --- K1.5 (R11 byte-identical): fold 32 partial rows -> xsum[C].
__global__ void k_reduce(const float* __restrict__ part, float* __restrict__ xsum) {
    const int c = blockIdx.x * blockDim.x + threadIdx.x;
    float a = 0.f;
#pragma unroll
    for (int t = 0; t < SPLITS; ++t) a += part[(size_t)t * C + c];
    xsum[c] = a;
}

// --- K2 (R7-frozen): one wave per (h, b-octet). 512 blocks x 256 = 2048 waves.
__global__ void __launch_bounds__(256) k_out(const float* __restrict__ xsum,
                                             const float* __restrict__ Wv,
                                             const float* __restrict__ bv,
                                             float* __restrict__ out) {
    const int wid  = (blockIdx.x * 256 + threadIdx.x) >> 6;  // [0, 2048)
    const int lane = threadIdx.x & 63;
    const int h    = wid >> 1;           // [0, 1024)
    const int bh   = (wid & 1) * 8;      // 0 or 8

    const float4* wr = (const float4*)(Wv + (size_t)h * H);  // 256 float4/row
    const float4 w0 = wr[lane], w1 = wr[lane + 64],
                 w2 = wr[lane + 128], w3 = wr[lane + 192];
    const float bvh = bv[h];

    float acc[8];
#pragma unroll
    for (int b = 0; b < 8; ++b) {
        const float4* xr = (const float4*)(xsum + (size_t)(bh + b) * H);
        const float4 a0 = xr[lane], a1 = xr[lane + 64],
                     a2 = xr[lane + 128], a3 = xr[lane + 192];
        acc[b] = a0.x * w0.x + a0.y * w0.y + a0.z * w0.z + a0.w * w0.w
               + a1.x * w1.x + a1.y * w1.y + a1.z * w1.z + a1.w * w1.w
               + a2.x * w2.x + a2.y * w2.y + a2.z * w2.z + a2.w * w2.w
               + a3.x * w3.x + a3.y * w3.y + a3.z * w3.z + a3.w * w3.w;
    }
#pragma unroll
    for (int b = 0; b < 8; ++b) {
#pragma unroll
        for (int off = 32; off; off >>= 1) acc[b] += __shfl_down(acc[b], off, 64);
    }
    if (lane == 0) {
#pragma unroll
        for (int b = 0; b < 8; ++b) {
            const int c = (bh + b) * H + h;
            out[c] = (xsum[c] + acc[b]) * (1.0f / (float)S) + bvh;
        }
    }
}

extern "C" void kernel_launch(void* const* d_in, const int* in_sizes, int n_in,
                              void* d_out, int out_size, void* d_ws, size_t ws_size,
                              hipStream_t stream) {
    const float* x  = (const float*)d_in[0];
    // d_in[1..4] (Wq,bq,Wk,bk) are provably unused (see header).
    const float* Wv = (const float*)d_in[5];
    const float* bv = (const float*)d_in[6];
    float* out = (float*)d_out;
    float* ws  = (float*)d_ws;

    float* part = ws;                       // [SPLITS][C]  = 2 MiB
    float* xsum = ws + (size_t)SPLITS * C;  // [C]

    // INSTRUMENTATION: 5 identical colsum dispatches (idempotent writes of
    // the same values -> deterministic output). dT vs R11 = 4*(colsum+gap).
    for (int rep = 0; rep < 5; ++rep) {
        k_colsum<<<dim3(C4 / 256, SPLITS), 256, 0, stream>>>(
            (const f4v*)x, (f4v*)part);
    }
    k_reduce<<<C / 256, 256, 0, stream>>>(part, xsum);
    k_out<<<512, 256, 0, stream>>>(xsum, Wv, bv, out);
}

// Round 14
// 51.441 us; speedup vs baseline: 1.3121x; 1.3121x over previous
//
#include <hip/hip_runtime.h>

// Algebraic collapse (verified exactly, absmax 0.0 across rounds):
//   softmax over the QUERY axis => sum_q attn[b,q,k] == 1 for all (b,k), so
//   context.mean(axis=0) = mean_k V[k,b,:] = xbar @ Wv.T + bv, and
//   out[b,h] = xbar[b,h] + sum_j xbar[b,j]*Wv[h,j] + bv[h],  xbar = x.mean(0).
//   Wq, bq, Wk, bk drop out of the output entirely.
// Lessons:
//   R2: NO cooperative grid.sync on MI355X (~100us/sync).
//   R3-R12 colsum scan: best = 512blk/4KB/SCHUNK=32/part=2MiB + nt (23.6us).
//   R13 replication: colsum+gap = 10.97us ~= 91-95% of fill-rate floor for
//     its 69MB => colsum CLOSED. Tail (reduce+out+gaps+fixed) = 12.6us —
//     model says kernels ~4us => suspect ~8us fixed graph/launch overhead.
//   R7: k_out wave-per-(h,8b) Wv-register-reuse. FROZEN.
//   R14 INSTRUMENTATION: replicate (reduce,out) 5x. Delta/4 = T (per-rep
//     tail incl gaps); F = 12.6 - T = fixed overhead. Splits "tail is slow"
//     vs "harness overhead" hypotheses exactly.

constexpr int S = 1024;
constexpr int B = 16;
constexpr int H = 1024;
constexpr int C = B * H;            // 16384 columns when x is viewed [S][B*H]
constexpr int C4 = C / 4;           // 4096 float4 columns
constexpr int SPLITS = 32;          // S-axis split (frozen good value)
constexpr int SCHUNK = S / SPLITS;  // 32 rows per block

typedef float f4v __attribute__((ext_vector_type(4)));

// --- K1 (R11 byte-identical): partial column sums, nt loads.
// grid (16, 32) = 512 blocks, block 256.
__global__ void __launch_bounds__(256) k_colsum(const f4v* __restrict__ x4,
                                                f4v* __restrict__ part4) {
    const int c4 = blockIdx.x * 256 + threadIdx.x;   // [0, 4096)
    const int split = blockIdx.y;
    const f4v* p = x4 + (size_t)split * SCHUNK * C4 + c4;
    f4v a = (f4v){0.f, 0.f, 0.f, 0.f};
#pragma unroll
    for (int i = 0; i < SCHUNK; ++i) {
        f4v v = __builtin_nontemporal_load(p + (size_t)i * C4);
        a += v;   // same per-column add order as R11
    }
    part4[(size_t)split * C4 + c4] = a;
}

// --- K1.5 (R11 byte-identical): fold 32 partial rows -> xsum[C].
__global__ void k_reduce(const float* __restrict__ part, float* __restrict__ xsum) {
    const int c = blockIdx.x * blockDim.x + threadIdx.x;
    float a = 0.f;
#pragma unroll
    for (int t = 0; t < SPLITS; ++t) a += part[(size_t)t * C + c];
    xsum[c] = a;
}

// --- K2 (R7-frozen, byte-identical): one wave per (h, b-octet).
__global__ void __launch_bounds__(256) k_out(const float* __restrict__ xsum,
                                             const float* __restrict__ Wv,
                                             const float* __restrict__ bv,
                                             float* __restrict__ out) {
    const int wid  = (blockIdx.x * 256 + threadIdx.x) >> 6;  // [0, 2048)
    const int lane = threadIdx.x & 63;
    const int h    = wid >> 1;           // [0, 1024)
    const int bh   = (wid & 1) * 8;      // 0 or 8

    const float4* wr = (const float4*)(Wv + (size_t)h * H);  // 256 float4/row
    const float4 w0 = wr[lane], w1 = wr[lane + 64],
                 w2 = wr[lane + 128], w3 = wr[lane + 192];
    const float bvh = bv[h];

    float acc[8];
#pragma unroll
    for (int b = 0; b < 8; ++b) {
        const float4* xr = (const float4*)(xsum + (size_t)(bh + b) * H);
        const float4 a0 = xr[lane], a1 = xr[lane + 64],
                     a2 = xr[lane + 128], a3 = xr[lane + 192];
        acc[b] = a0.x * w0.x + a0.y * w0.y + a0.z * w0.z + a0.w * w0.w
               + a1.x * w1.x + a1.y * w1.y + a1.z * w1.z + a1.w * w1.w
               + a2.x * w2.x + a2.y * w2.y + a2.z * w2.z + a2.w * w2.w
               + a3.x * w3.x + a3.y * w3.y + a3.z * w3.z + a3.w * w3.w;
    }
#pragma unroll
    for (int b = 0; b < 8; ++b) {
#pragma unroll
        for (int off = 32; off; off >>= 1) acc[b] += __shfl_down(acc[b], off, 64);
    }
    if (lane == 0) {
#pragma unroll
        for (int b = 0; b < 8; ++b) {
            const int c = (bh + b) * H + h;
            out[c] = (xsum[c] + acc[b]) * (1.0f / (float)S) + bvh;
        }
    }
}

extern "C" void kernel_launch(void* const* d_in, const int* in_sizes, int n_in,
                              void* d_out, int out_size, void* d_ws, size_t ws_size,
                              hipStream_t stream) {
    const float* x  = (const float*)d_in[0];
    // d_in[1..4] (Wq,bq,Wk,bk) are provably unused (see header).
    const float* Wv = (const float*)d_in[5];
    const float* bv = (const float*)d_in[6];
    float* out = (float*)d_out;
    float* ws  = (float*)d_ws;

    float* part = ws;                       // [SPLITS][C]  = 2 MiB
    float* xsum = ws + (size_t)SPLITS * C;  // [C]

    k_colsum<<<dim3(C4 / 256, SPLITS), 256, 0, stream>>>(
        (const f4v*)x, (f4v*)part);
    // INSTRUMENTATION: 5 identical (reduce,out) pairs — idempotent,
    // deterministic. Delta vs R11 = 4*(reduce + out + 2 gaps).
    for (int rep = 0; rep < 5; ++rep) {
        k_reduce<<<C / 256, 256, 0, stream>>>(part, xsum);
        k_out<<<512, 256, 0, stream>>>(xsum, Wv, bv, out);
    }
}

// Round 15
// 26.233 us; speedup vs baseline: 2.5729x; 1.9609x over previous
//
#include <hip/hip_runtime.h>

// Algebraic collapse (verified exactly, absmax 0.0 across rounds):
//   softmax over the QUERY axis => sum_q attn[b,q,k] == 1 for all (b,k), so
//   context.mean(axis=0) = mean_k V[k,b,:] = xbar @ Wv.T + bv, and
//   out[b,h] = xbar[b,h] + sum_j xbar[b,j]*Wv[h,j] + bv[h],  xbar = x.mean(0).
//   Wq, bq, Wk, bk drop out of the output entirely.
// Budget (R13/R14 replication-measured, total 23.6us):
//   colsum+gap 10.97us (~93% of fill-rate floor for 69MB -> CLOSED)
//   tail (reduce+out+2gaps) 6.96us  <- only attackable fat
//   fixed graph/launch overhead 5.67us (unattackable)
// Lessons: R2 no grid.sync (~100us). R3-R12 colsum scan: 512blk/4KB/
//   SCHUNK=32/part=2MiB + nt = optimum; occupancy & contiguity not limiting.
//   Fusion closed: fold-in-out duplicates part reads; atomics need per-call
//   zeroed ws (not re-poisoned between replays).
// R15: tail polish. k_reduce: 8xfloat4 + 4-way LDS tree (was 32 scalar
//   chain). k_out: wave per h, ALL 16 b (Wv read once per row, 68 indep
//   loads of ILP/wave; occupancy 1 wave/SIMD is the known risk).

constexpr int S = 1024;
constexpr int B = 16;
constexpr int H = 1024;
constexpr int C = B * H;            // 16384 columns when x is viewed [S][B*H]
constexpr int C4 = C / 4;           // 4096 float4 columns
constexpr int SPLITS = 32;          // S-axis split (frozen good value)
constexpr int SCHUNK = S / SPLITS;  // 32 rows per block

typedef float f4v __attribute__((ext_vector_type(4)));

// --- K1 (R11 byte-identical, FROZEN): partial column sums, nt loads.
// grid (16, 32) = 512 blocks, block 256.
__global__ void __launch_bounds__(256) k_colsum(const f4v* __restrict__ x4,
                                                f4v* __restrict__ part4) {
    const int c4 = blockIdx.x * 256 + threadIdx.x;   // [0, 4096)
    const int split = blockIdx.y;
    const f4v* p = x4 + (size_t)split * SCHUNK * C4 + c4;
    f4v a = (f4v){0.f, 0.f, 0.f, 0.f};
#pragma unroll
    for (int i = 0; i < SCHUNK; ++i) {
        f4v v = __builtin_nontemporal_load(p + (size_t)i * C4);
        a += v;   // same per-column add order as R11
    }
    part4[(size_t)split * C4 + c4] = a;
}

// --- K1.5 (NEW): fold 32 partial rows -> xsum[C], float4 + 4-way tree.
// grid 64, block 256. thread = (c4 = bx*64 + (t&63), quarter q = t>>6).
// Each thread sums 8 partials (float4); quarters combined ((q0+q1)+(q2+q3)).
__global__ void __launch_bounds__(256) k_reduce(const f4v* __restrict__ part4,
                                                f4v* __restrict__ xsum4) {
    __shared__ f4v buf[256];
    const int t  = threadIdx.x;
    const int c4 = blockIdx.x * 64 + (t & 63);   // [0, 4096)
    const int q  = t >> 6;                       // [0, 4)
    f4v s = (f4v){0.f, 0.f, 0.f, 0.f};
#pragma unroll
    for (int i = 0; i < 8; ++i)
        s += part4[(size_t)(q * 8 + i) * C4 + c4];
    buf[t] = s;
    __syncthreads();
    if (q == 0) {
        f4v r = (buf[t] + buf[t + 64]) + (buf[t + 128] + buf[t + 192]);
        xsum4[c4] = r;
    }
}

// --- K2 (NEW): one wave per h, ALL 16 b. 256 blocks x 256 thr = 1024 waves.
// Wv row fetched exactly once (4 MiB total); 16 independent acc chains.
__global__ void __launch_bounds__(256) k_out(const float* __restrict__ xsum,
                                             const float* __restrict__ Wv,
                                             const float* __restrict__ bv,
                                             float* __restrict__ out) {
    const int w    = threadIdx.x >> 6;           // wave in block [0,4)
    const int lane = threadIdx.x & 63;
    const int h    = blockIdx.x * 4 + w;         // [0, 1024)

    const float4* wr = (const float4*)(Wv + (size_t)h * H);  // 256 float4/row
    const float4 w0 = wr[lane], w1 = wr[lane + 64],
                 w2 = wr[lane + 128], w3 = wr[lane + 192];
    const float bvh = bv[h];

    float acc[16];
#pragma unroll
    for (int b = 0; b < 16; ++b) {
        const float4* xr = (const float4*)(xsum + (size_t)b * H);
        const float4 a0 = xr[lane], a1 = xr[lane + 64],
                     a2 = xr[lane + 128], a3 = xr[lane + 192];
        acc[b] = a0.x * w0.x + a0.y * w0.y + a0.z * w0.z + a0.w * w0.w
               + a1.x * w1.x + a1.y * w1.y + a1.z * w1.z + a1.w * w1.w
               + a2.x * w2.x + a2.y * w2.y + a2.z * w2.z + a2.w * w2.w
               + a3.x * w3.x + a3.y * w3.y + a3.z * w3.z + a3.w * w3.w;
    }
#pragma unroll
    for (int b = 0; b < 16; ++b) {
#pragma unroll
        for (int off = 32; off; off >>= 1) acc[b] += __shfl_down(acc[b], off, 64);
    }
    if (lane == 0) {
#pragma unroll
        for (int b = 0; b < 16; ++b) {
            const int c = b * H + h;
            out[c] = (xsum[c] + acc[b]) * (1.0f / (float)S) + bvh;
        }
    }
}

extern "C" void kernel_launch(void* const* d_in, const int* in_sizes, int n_in,
                              void* d_out, int out_size, void* d_ws, size_t ws_size,
                              hipStream_t stream) {
    const float* x  = (const float*)d_in[0];
    // d_in[1..4] (Wq,bq,Wk,bk) are provably unused (see header).
    const float* Wv = (const float*)d_in[5];
    const float* bv = (const float*)d_in[6];
    float* out = (float*)d_out;
    float* ws  = (float*)d_ws;

    float* part = ws;                       // [SPLITS][C]  = 2 MiB
    float* xsum = ws + (size_t)SPLITS * C;  // [C]

    k_colsum<<<dim3(C4 / 256, SPLITS), 256, 0, stream>>>(
        (const f4v*)x, (f4v*)part);
    k_reduce<<<64, 256, 0, stream>>>((const f4v*)part, (f4v*)xsum);
    k_out<<<256, 256, 0, stream>>>(xsum, Wv, bv, out);
}

// Round 16
// 23.465 us; speedup vs baseline: 2.8763x; 1.1179x over previous
//
#include <hip/hip_runtime.h>

// Algebraic collapse (verified exactly, absmax 0.0 across rounds):
//   softmax over the QUERY axis => sum_q attn[b,q,k] == 1 for all (b,k), so
//   context.mean(axis=0) = mean_k V[k,b,:] = xbar @ Wv.T + bv, and
//   out[b,h] = xbar[b,h] + sum_j xbar[b,j]*Wv[h,j] + bv[h],  xbar = x.mean(0).
//   Wq, bq, Wk, bk drop out of the output entirely.
// FINAL BUDGET (replication-measured R13/R14, total 23.6us):
//   colsum+gap 10.97us  = 93-95% of machine-demonstrated rate for its 66MB
//                         (m13 copy ceiling). CLOSED.
//   tail 6.96us         = reduce ~1 + out ~2.2 + 2 gaps ~3. Fold dispatch
//                         irreducible (global xsum dependency; no grid sync
//                         per R2; part-duplication costs +15us L2). CLOSED.
//   fixed overhead 5.67us = graph replay/launch ramp. Unattackable.
// Failed polish attempts confirming closure: R10 width +3.3, R12 occupancy
//   +0.2, R15 tail-polish +2.6. Best-config repeat band: 23.6-23.9us.
// This is the R11-exact kernel (best, 3x reproduced): 512blk/4KB-run/
//   SCHUNK=32/part=2MiB colsum with nontemporal loads; 32-deep fold;
//   wave-per-(h,8b) k_out with Wv register reuse.

constexpr int S = 1024;
constexpr int B = 16;
constexpr int H = 1024;
constexpr int C = B * H;            // 16384 columns when x is viewed [S][B*H]
constexpr int C4 = C / 4;           // 4096 float4 columns
constexpr int SPLITS = 32;          // S-axis split (frozen good value)
constexpr int SCHUNK = S / SPLITS;  // 32 rows per block

typedef float f4v __attribute__((ext_vector_type(4)));

// --- K1: partial column sums, nt loads. grid (16, 32) = 512 blocks, block 256.
__global__ void __launch_bounds__(256) k_colsum(const f4v* __restrict__ x4,
                                                f4v* __restrict__ part4) {
    const int c4 = blockIdx.x * 256 + threadIdx.x;   // [0, 4096)
    const int split = blockIdx.y;
    const f4v* p = x4 + (size_t)split * SCHUNK * C4 + c4;
    f4v a = (f4v){0.f, 0.f, 0.f, 0.f};
#pragma unroll
    for (int i = 0; i < SCHUNK; ++i) {
        f4v v = __builtin_nontemporal_load(p + (size_t)i * C4);
        a += v;
    }
    part4[(size_t)split * C4 + c4] = a;
}

// --- K1.5: fold 32 partial rows -> xsum[C]. 64 blocks, coalesced.
__global__ void k_reduce(const float* __restrict__ part, float* __restrict__ xsum) {
    const int c = blockIdx.x * blockDim.x + threadIdx.x;
    float a = 0.f;
#pragma unroll
    for (int t = 0; t < SPLITS; ++t) a += part[(size_t)t * C + c];
    xsum[c] = a;
}

// --- K2: one wave per (h, b-octet). 512 blocks x 256 = 2048 waves.
__global__ void __launch_bounds__(256) k_out(const float* __restrict__ xsum,
                                             const float* __restrict__ Wv,
                                             const float* __restrict__ bv,
                                             float* __restrict__ out) {
    const int wid  = (blockIdx.x * 256 + threadIdx.x) >> 6;  // [0, 2048)
    const int lane = threadIdx.x & 63;
    const int h    = wid >> 1;           // [0, 1024)
    const int bh   = (wid & 1) * 8;      // 0 or 8

    const float4* wr = (const float4*)(Wv + (size_t)h * H);  // 256 float4/row
    const float4 w0 = wr[lane], w1 = wr[lane + 64],
                 w2 = wr[lane + 128], w3 = wr[lane + 192];
    const float bvh = bv[h];

    float acc[8];
#pragma unroll
    for (int b = 0; b < 8; ++b) {
        const float4* xr = (const float4*)(xsum + (size_t)(bh + b) * H);
        const float4 a0 = xr[lane], a1 = xr[lane + 64],
                     a2 = xr[lane + 128], a3 = xr[lane + 192];
        acc[b] = a0.x * w0.x + a0.y * w0.y + a0.z * w0.z + a0.w * w0.w
               + a1.x * w1.x + a1.y * w1.y + a1.z * w1.z + a1.w * w1.w
               + a2.x * w2.x + a2.y * w2.y + a2.z * w2.z + a2.w * w2.w
               + a3.x * w3.x + a3.y * w3.y + a3.z * w3.z + a3.w * w3.w;
    }
#pragma unroll
    for (int b = 0; b < 8; ++b) {
#pragma unroll
        for (int off = 32; off; off >>= 1) acc[b] += __shfl_down(acc[b], off, 64);
    }
    if (lane == 0) {
#pragma unroll
        for (int b = 0; b < 8; ++b) {
            const int c = (bh + b) * H + h;
            out[c] = (xsum[c] + acc[b]) * (1.0f / (float)S) + bvh;
        }
    }
}

extern "C" void kernel_launch(void* const* d_in, const int* in_sizes, int n_in,
                              void* d_out, int out_size, void* d_ws, size_t ws_size,
                              hipStream_t stream) {
    const float* x  = (const float*)d_in[0];
    // d_in[1..4] (Wq,bq,Wk,bk) are provably unused (see header).
    const float* Wv = (const float*)d_in[5];
    const float* bv = (const float*)d_in[6];
    float* out = (float*)d_out;
    float* ws  = (float*)d_ws;

    float* part = ws;                       // [SPLITS][C]  = 2 MiB
    float* xsum = ws + (size_t)SPLITS * C;  // [C]

    k_colsum<<<dim3(C4 / 256, SPLITS), 256, 0, stream>>>(
        (const f4v*)x, (f4v*)part);
    k_reduce<<<C / 256, 256, 0, stream>>>(part, xsum);
    k_out<<<512, 256, 0, stream>>>(xsum, Wv, bv, out);
}